// Round 8
// baseline (179.507 us; speedup 1.0000x reference)
//
#include <hip/hip_runtime.h>
#include <hip/hip_bf16.h>
#include <math.h>

#define EPSF 1e-5f

using short2v = __attribute__((ext_vector_type(2))) short;
using short4v = __attribute__((ext_vector_type(4))) short;
using short8 = __attribute__((ext_vector_type(8))) short;
using f32x4 = __attribute__((ext_vector_type(4))) float;

__device__ inline short bfbits(float x) {
  __hip_bfloat16 h = __float2bfloat16(x);
  return __builtin_bit_cast(short, h);
}
__device__ inline float bf2f(short s) {
  unsigned u = ((unsigned)(unsigned short)s) << 16;
  return __builtin_bit_cast(float, u);
}

// ---------------------------------------------------------------------------
// prep: fold BN into weights/bias, bf16 weights (padded), transposed dwconv
// tables. Q rows absorb 0.25*log2(e) so attention uses exp2 directly.
// ---------------------------------------------------------------------------
__global__ __launch_bounds__(256) void prep_kernel(
    const float* __restrict__ qkv_w, const float* __restrict__ qkv_bn,
    const float* __restrict__ proj_w, const float* __restrict__ proj_bn,
    const float* __restrict__ fc1_w, const float* __restrict__ fc2_w,
    const float* __restrict__ pe_w, const float* __restrict__ pe_bn,
    const float* __restrict__ dw_w, const float* __restrict__ dw_b,
    short* __restrict__ wq, float* __restrict__ bq, short* __restrict__ wpj,
    float* __restrict__ bpj, short* __restrict__ wf1, short* __restrict__ wf2,
    float* __restrict__ pwT, float* __restrict__ pbv, float* __restrict__ wdT,
    float* __restrict__ dbv) {
  int id = blockIdx.x * 256 + threadIdx.x;
  if (id < 131072) {
    int o = id >> 8, k = id & 255;
    float g = qkv_bn[o], bb = qkv_bn[512 + o], m = qkv_bn[1024 + o],
          v = qkv_bn[1536 + o];
    float s = g * rsqrtf(v + EPSF);
    float s2 = ((o & 63) < 16) ? 0.25f * 1.44269504088896f : 1.0f;
    wq[id] = bfbits(qkv_w[id] * s * s2);
    if (k == 0) bq[o] = (bb - m * s) * s2;
  } else if (id < 196608) {
    int i = id - 131072;
    int o = i >> 8, k = i & 255;
    float g = proj_bn[o], bb = proj_bn[256 + o], m = proj_bn[512 + o],
          v = proj_bn[768 + o];
    float s = g * rsqrtf(v + EPSF);
    wpj[i] = bfbits(proj_w[i] * s);
    if (k == 0) bpj[o] = bb - m * s;
  } else if (id < 294912) {
    int i = id - 196608;
    int o = i >> 8, k = i & 255;
    wf1[i] = bfbits(o < 340 ? fc1_w[o * 256 + k] : 0.f);
  } else if (id < 344064) {
    int i = id - 294912;
    int o = i / 192, k = i - o * 192;
    wf2[i] = bfbits(k < 170 ? fc2_w[o * 170 + k] : 0.f);
  } else if (id < 346368) {
    int i = id - 344064;
    int c = i & 255, tap = i >> 8;
    float g = pe_bn[c], bb = pe_bn[256 + c], m = pe_bn[512 + c],
          v = pe_bn[768 + c];
    float s = g * rsqrtf(v + EPSF);
    pwT[tap * 256 + c] = pe_w[c * 9 + tap] * s;
    if (tap == 0) pbv[c] = bb - m * s;
  } else if (id < 348096) {
    int i = id - 346368;
    int c = i % 192, tap = i / 192;
    wdT[tap * 192 + c] = (c < 170) ? dw_w[c * 9 + tap] : 0.f;
    if (tap == 0) dbv[c] = (c < 170) ? dw_b[c] : 0.f;
  }
}

// ---------------------------------------------------------------------------
// LN1: x f32 [b][c][n] -> xn bf16 channels-last [b][n][256].
// ---------------------------------------------------------------------------
__global__ __launch_bounds__(256) void ln1_kernel(
    const float* __restrict__ x, const float* __restrict__ gamma,
    const float* __restrict__ beta, short* __restrict__ xn) {
  __shared__ float s_sum[16][16];
  __shared__ float s_sq[16][16];
  int t = threadIdx.x;
  int nl = t & 15, cg = t >> 4;
  int p0 = blockIdx.x * 16;
  int b = p0 >> 10;
  int n = (p0 & 1023) + nl;
  const float* xp = x + ((size_t)b * 256 + cg * 16) * 1024 + n;
  float v[16];
  float sum = 0.f, sq = 0.f;
#pragma unroll
  for (int i = 0; i < 16; ++i) {
    float val = xp[(size_t)i * 1024];
    v[i] = val;
    sum += val;
    sq += val * val;
  }
  s_sum[cg][nl] = sum;
  s_sq[cg][nl] = sq;
  __syncthreads();
  float ts = 0.f, tq = 0.f;
#pragma unroll
  for (int g = 0; g < 16; ++g) {
    ts += s_sum[g][nl];
    tq += s_sq[g][nl];
  }
  float mu = ts * (1.f / 256.f);
  float var = tq * (1.f / 256.f) - mu * mu;
  float rs = rsqrtf(var + EPSF);
  short8 pk[2];
#pragma unroll
  for (int i = 0; i < 16; ++i) {
    int c = cg * 16 + i;
    pk[i >> 3][i & 7] = bfbits((v[i] - mu) * rs * gamma[c] + beta[c]);
  }
  short* op = xn + ((size_t)b * 1024 + n) * 256 + cg * 16;
  *reinterpret_cast<short8*>(op) = pk[0];
  *reinterpret_cast<short8*>(op + 8) = pk[1];
}

// ---------------------------------------------------------------------------
// LN2: x1 f32 CL [pos][256] -> xn2 bf16 CL.
// ---------------------------------------------------------------------------
__global__ __launch_bounds__(256) void ln2_kernel(
    const float* __restrict__ x1, const float* __restrict__ gamma,
    const float* __restrict__ beta, short* __restrict__ xn2) {
  int t = threadIdx.x;
  int lane = t & 63, w = t >> 6;
  f32x4 gv = *reinterpret_cast<const f32x4*>(&gamma[lane * 4]);
  f32x4 bv = *reinterpret_cast<const f32x4*>(&beta[lane * 4]);
#pragma unroll
  for (int it = 0; it < 4; ++it) {
    size_t pos = blockIdx.x * 16 + w * 4 + it;
    f32x4 xv = *reinterpret_cast<const f32x4*>(&x1[pos * 256 + lane * 4]);
    float s = (xv[0] + xv[1]) + (xv[2] + xv[3]);
    float q = (xv[0] * xv[0] + xv[1] * xv[1]) + (xv[2] * xv[2] + xv[3] * xv[3]);
#pragma unroll
    for (int off = 1; off < 64; off <<= 1) {
      s += __shfl_xor(s, off);
      q += __shfl_xor(q, off);
    }
    float mu = s * (1.f / 256.f);
    float var = q * (1.f / 256.f) - mu * mu;
    float rs = rsqrtf(var + EPSF);
    short4v o;
#pragma unroll
    for (int e = 0; e < 4; ++e)
      o[e] = bfbits((xv[e] - mu) * rs * gv[e] + bv[e]);
    *reinterpret_cast<short4v*>(&xn2[pos * 256 + lane * 4]) = o;
  }
}

// ---------------------------------------------------------------------------
// MFMA GEMM v6: tile 64n x 128o, BK=64, 4 waves (2o x 2n), register-
// prefetched staging. MODE 0: out bf16 CL stride RS (+bias).
// MODE 1: out f32 CL 256 (+bias + x channel-major). MODE 2: f32 CM d_out
// (+bias + x1 f32CL + xn2 bf16CL). MODE 3: MODE 0 + dual-write V channels
// to vT per-head channel-major [b*8+h][d][n].
// ---------------------------------------------------------------------------
template <int MODE>
__global__ __launch_bounds__(256) void gemm6_kernel(
    const short* __restrict__ X, const short* __restrict__ W,
    const float* __restrict__ bias, const float* __restrict__ addCM,
    const float* __restrict__ add1CL, const short* __restrict__ add2CL,
    void* __restrict__ out, short* __restrict__ vTout, int OC, int K, int OT,
    int KS, int RS) {
  __shared__ short Wl[128][72];
  __shared__ short Xl[64][72];
  int bx = blockIdx.x;
  int ot = bx % OT;
  int ntb = bx / OT;
  int b = ntb >> 4;
  int n0 = (ntb & 15) * 64;
  int o0 = ot * 128;
  int t = threadIdx.x;
  int lane = t & 63, w = t >> 6;
  int wo = w >> 1, wn = w & 1;
  int g = lane >> 4, r = lane & 15;
  int rw = t >> 1, cw = (t & 1) * 32;
  int rx = t >> 2, cx = (t & 3) * 16;
  size_t bN = (size_t)b * 1024;
  const short* Wp = W + (size_t)(o0 + rw) * K + cw;
  const short* Xp = X + (bN + n0 + rx) * KS + cx;
  f32x4 acc[4][2] = {};
  int nsteps = K >> 6;
  short8 wreg[4], xreg[2];
#pragma unroll
  for (int e = 0; e < 4; ++e)
    wreg[e] = *reinterpret_cast<const short8*>(Wp + e * 8);
#pragma unroll
  for (int e = 0; e < 2; ++e)
    xreg[e] = *reinterpret_cast<const short8*>(Xp + e * 8);
  for (int ks = 0; ks < nsteps; ++ks) {
#pragma unroll
    for (int e = 0; e < 4; ++e)
      *reinterpret_cast<short8*>(&Wl[rw][cw + e * 8]) = wreg[e];
#pragma unroll
    for (int e = 0; e < 2; ++e)
      *reinterpret_cast<short8*>(&Xl[rx][cx + e * 8]) = xreg[e];
    __syncthreads();
    if (ks + 1 < nsteps) {
      int ko = (ks + 1) << 6;
#pragma unroll
      for (int e = 0; e < 4; ++e)
        wreg[e] = *reinterpret_cast<const short8*>(Wp + ko + e * 8);
#pragma unroll
      for (int e = 0; e < 2; ++e)
        xreg[e] = *reinterpret_cast<const short8*>(Xp + ko + e * 8);
    }
#pragma unroll
    for (int kk = 0; kk < 2; ++kk) {
      short8 a[4], bb[2];
#pragma unroll
      for (int i = 0; i < 4; ++i)
        a[i] = *reinterpret_cast<const short8*>(
            &Wl[wo * 64 + i * 16 + r][kk * 32 + g * 8]);
#pragma unroll
      for (int j = 0; j < 2; ++j)
        bb[j] = *reinterpret_cast<const short8*>(
            &Xl[wn * 32 + j * 16 + r][kk * 32 + g * 8]);
#pragma unroll
      for (int i = 0; i < 4; ++i)
#pragma unroll
        for (int j = 0; j < 2; ++j)
          acc[i][j] = __builtin_amdgcn_mfma_f32_16x16x32_bf16(
              a[i], bb[j], acc[i][j], 0, 0, 0);
    }
    __syncthreads();
  }
#pragma unroll
  for (int i = 0; i < 4; ++i) {
#pragma unroll
    for (int j = 0; j < 2; ++j) {
      int oq = o0 + wo * 64 + i * 16 + g * 4;
      if (oq >= OC) continue;
      int n = n0 + wn * 32 + j * 16 + r;
      f32x4 bv = *reinterpret_cast<const f32x4*>(&bias[oq]);
      f32x4 res;
#pragma unroll
      for (int rr = 0; rr < 4; ++rr) res[rr] = acc[i][j][rr] + bv[rr];
      if constexpr (MODE == 0 || MODE == 3) {
        short4v s;
#pragma unroll
        for (int rr = 0; rr < 4; ++rr) s[rr] = bfbits(res[rr]);
        *reinterpret_cast<short4v*>((short*)out + (bN + n) * RS + oq) = s;
        if constexpr (MODE == 3) {
          int sub = oq & 63;
          if (sub >= 32) {
            int head = oq >> 6, d = sub - 32;
            size_t vb = ((size_t)(b * 8 + head) * 32 + d) * 1024 + n;
            vTout[vb] = s[0];
            vTout[vb + 1024] = s[1];
            vTout[vb + 2048] = s[2];
            vTout[vb + 3072] = s[3];
          }
        }
      } else if constexpr (MODE == 1) {
#pragma unroll
        for (int rr = 0; rr < 4; ++rr)
          res[rr] += addCM[((size_t)b * 256 + oq + rr) * 1024 + n];
        *reinterpret_cast<f32x4*>((float*)out + (bN + n) * 256 + oq) = res;
      } else {
        f32x4 a1v = *reinterpret_cast<const f32x4*>(&add1CL[(bN + n) * 256 + oq]);
        short4v a2v = *reinterpret_cast<const short4v*>(&add2CL[(bN + n) * 256 + oq]);
#pragma unroll
        for (int rr = 0; rr < 4; ++rr) {
          float v = res[rr] + a1v[rr] + bf2f(a2v[rr]);
          ((float*)out)[((size_t)b * 256 + oq + rr) * 1024 + n] = v;
        }
      }
    }
  }
}

// ---------------------------------------------------------------------------
// MFMA flash attention v6 + fused PE epilogue.
// Round-6-proven numerics (defer-max exp2 softmax, per-chunk l update,
// __float2bfloat16 packing) on the new staging structure: KVBLK=128 staged
// per chunk (2 sub-blocks of 64 m), double-buffered K/V with ONE barrier
// per chunk; V staged from vT (per-head CM) as pure b128 copies; Q fragment
// direct from global (kd 16..31 zero on g>=2 lanes, identical to round 6's
// physical zero-pad). Separate Ol array (no LDS aliasing). grid = 1024,
// h fastest (XCD-local K/V).
// ---------------------------------------------------------------------------
__global__ __launch_bounds__(256) void attn6_kernel(
    const short* __restrict__ qkv, const short* __restrict__ vT,
    const float* __restrict__ pwT, const float* __restrict__ pbv,
    short* __restrict__ obf) {
  __shared__ short Kl[2][128][24];
  __shared__ short Vl[2][32][136];
  __shared__ short Ol[64][36];
  int blk = blockIdx.x;
  int h = blk & 7, qt = (blk >> 3) & 15, b = blk >> 7;
  size_t bN = (size_t)b * 1024;
  const short* base = qkv + bN * 512 + h * 64;
  const short* vTb = vT + (size_t)(b * 8 + h) * 32 * 1024;
  int t = threadIdx.x;
  int lane = t & 63, w = t >> 6;
  int g = lane >> 4, r = lane & 15;
  int q0 = qt * 64;
  // Q fragment direct from global (kd 16..31 are zero -> g>=2 lanes zero)
  short8 qf = {};
  if (g < 2)
    qf = *reinterpret_cast<const short8*>(
        &base[(size_t)(q0 + w * 16 + r) * 512 + g * 8]);
  // staging indices
  int km = t >> 1, kh = (t & 1) * 8;
  int vd = t >> 3, vm = (t & 7) * 16;
  // preload chunk 0
  short8 kreg =
      *reinterpret_cast<const short8*>(&base[(size_t)km * 512 + 16 + kh]);
  short8 vreg0 = *reinterpret_cast<const short8*>(&vTb[(size_t)vd * 1024 + vm]);
  short8 vreg1 =
      *reinterpret_cast<const short8*>(&vTb[(size_t)vd * 1024 + vm + 8]);
  float M = -3e38f, l = 0.f;
  f32x4 O0 = {}, O1 = {};
  for (int ch = 0; ch < 8; ++ch) {
    int cur = ch & 1;
    *reinterpret_cast<short8*>(&Kl[cur][km][kh]) = kreg;
    *reinterpret_cast<short8*>(&Vl[cur][vd][vm]) = vreg0;
    *reinterpret_cast<short8*>(&Vl[cur][vd][vm + 8]) = vreg1;
    __syncthreads();
    if (ch + 1 < 8) {
      int m0 = (ch + 1) * 128;
      kreg = *reinterpret_cast<const short8*>(
          &base[(size_t)(m0 + km) * 512 + 16 + kh]);
      vreg0 =
          *reinterpret_cast<const short8*>(&vTb[(size_t)vd * 1024 + m0 + vm]);
      vreg1 = *reinterpret_cast<const short8*>(
          &vTb[(size_t)vd * 1024 + m0 + vm + 8]);
    }
#pragma unroll
    for (int sub = 0; sub < 2; ++sub) {
      int mb = sub * 64;
      f32x4 s4[4];
#pragma unroll
      for (int mt = 0; mt < 4; ++mt) {
        short8 af = {};
        if (g < 2)
          af = *reinterpret_cast<const short8*>(
              &Kl[cur][mb + mt * 16 + r][g * 8]);
        f32x4 z = {};
        s4[mt] = __builtin_amdgcn_mfma_f32_16x16x32_bf16(af, qf, z, 0, 0, 0);
      }
      float pm = -3e38f;
#pragma unroll
      for (int mt = 0; mt < 4; ++mt)
        pm = fmaxf(pm, fmaxf(fmaxf(s4[mt][0], s4[mt][1]),
                             fmaxf(s4[mt][2], s4[mt][3])));
      pm = fmaxf(pm, __shfl_xor(pm, 16));
      pm = fmaxf(pm, __shfl_xor(pm, 32));
      bool full = !__all(pm - M <= 8.f);  // T13: defer rescale
      float Mn = full ? fmaxf(M, pm) : M;
      float f = full ? exp2f(M - Mn) : 1.f;
      M = Mn;
      float sc = 0.f;
      short8 pa[4];
#pragma unroll
      for (int mt = 0; mt < 4; ++mt) {
        float p0 = exp2f(s4[mt][0] - Mn);
        float p1 = exp2f(s4[mt][1] - Mn);
        float p2 = exp2f(s4[mt][2] - Mn);
        float p3 = exp2f(s4[mt][3] - Mn);
        sc += (p0 + p1) + (p2 + p3);
        pa[mt] = (short8){bfbits(p0), bfbits(p1), bfbits(p2), bfbits(p3),
                          0, 0, 0, 0};
      }
      sc += __shfl_xor(sc, 16);
      sc += __shfl_xor(sc, 32);
      l = l * f + sc;
      if (full) {
#pragma unroll
        for (int rr = 0; rr < 4; ++rr) {
          float fr = __shfl(f, g * 4 + rr);
          O0[rr] *= fr;
          O1[rr] *= fr;
        }
      }
#pragma unroll
      for (int mt = 0; mt < 4; ++mt) {
        short4v v0 = *reinterpret_cast<const short4v*>(
            &Vl[cur][r][mb + mt * 16 + g * 4]);
        short4v v1 = *reinterpret_cast<const short4v*>(
            &Vl[cur][16 + r][mb + mt * 16 + g * 4]);
        short8 b0 = {v0[0], v0[1], v0[2], v0[3], 0, 0, 0, 0};
        short8 b1 = {v1[0], v1[1], v1[2], v1[3], 0, 0, 0, 0};
        O0 = __builtin_amdgcn_mfma_f32_16x16x32_bf16(pa[mt], b0, O0, 0, 0, 0);
        O1 = __builtin_amdgcn_mfma_f32_16x16x32_bf16(pa[mt], b1, O1, 0, 0, 0);
      }
    }
  }
  // normalize, store to Ol (bf16)
#pragma unroll
  for (int rr = 0; rr < 4; ++rr) {
    float lr = __shfl(l, g * 4 + rr);
    float inv = 1.f / lr;
    int q = w * 16 + g * 4 + rr;
    Ol[q][r] = bfbits(O0[rr] * inv);
    Ol[q][16 + r] = bfbits(O1[rr] * inv);
  }
  __syncthreads();
  // fused PE epilogue: item = (q local, d-quad)
#pragma unroll
  for (int it = 0; it < 2; ++it) {
    int item = t + it * 256;
    int q = item & 63, dq = item >> 6;
    int n = q0 + q;
    int y = n >> 5, xx = n & 31;
    int cq = h * 32 + dq * 4;
    f32x4 s = *reinterpret_cast<const f32x4*>(&pbv[cq]);
#pragma unroll
    for (int dy = -1; dy <= 1; ++dy) {
      int yy = y + dy;
      if (yy < 0 || yy > 31) continue;
#pragma unroll
      for (int dx = -1; dx <= 1; ++dx) {
        int xw = xx + dx;
        if (xw < 0 || xw > 31) continue;
        int tap = (dy + 1) * 3 + (dx + 1);
        f32x4 wv = *reinterpret_cast<const f32x4*>(&pwT[tap * 256 + cq]);
        short4v vv = *reinterpret_cast<const short4v*>(
            &base[(size_t)(yy * 32 + xw) * 512 + 32 + dq * 4]);
#pragma unroll
        for (int e = 0; e < 4; ++e) s[e] += wv[e] * bf2f(vv[e]);
      }
    }
    short4v ov = *reinterpret_cast<const short4v*>(&Ol[q][dq * 4]);
    short4v res;
#pragma unroll
    for (int e = 0; e < 4; ++e) res[e] = bfbits(bf2f(ov[e]) + s[e]);
    *reinterpret_cast<short4v*>(&obf[(bN + n) * 256 + cq]) = res;
  }
}

// ---------------------------------------------------------------------------
// GLU v3 (channels-last, vectorized): act[n][192] = bf16(gelu(dwconv(a)+b)*g).
// ---------------------------------------------------------------------------
__global__ __launch_bounds__(256) void glu3_kernel(
    const short* __restrict__ h, const float* __restrict__ wdT,
    const float* __restrict__ dbv, short* __restrict__ act) {
  int t = threadIdx.x;
  int pos = blockIdx.x * 16 + (t >> 4);
  int c0 = (t & 15) * 12;
  int n = pos & 1023;
  int b = pos >> 10;
  int y = n >> 5, xx = n & 31;
  const short* hb = h + (size_t)b * 1024 * 352;
  float s[12];
#pragma unroll
  for (int e = 0; e < 12; ++e) s[e] = dbv[c0 + e];
#pragma unroll
  for (int dy = -1; dy <= 1; ++dy) {
    int yy = y + dy;
    if (yy < 0 || yy > 31) continue;
#pragma unroll
    for (int dx = -1; dx <= 1; ++dx) {
      int xw = xx + dx;
      if (xw < 0 || xw > 31) continue;
      int tap = (dy + 1) * 3 + (dx + 1);
      const float* wp = wdT + tap * 192 + c0;
      const short* ap = hb + (size_t)(yy * 32 + xw) * 352 + c0;
#pragma unroll
      for (int v4 = 0; v4 < 3; ++v4) {
        short4v av = *reinterpret_cast<const short4v*>(ap + v4 * 4);
        f32x4 wv = *reinterpret_cast<const f32x4*>(wp + v4 * 4);
#pragma unroll
        for (int e = 0; e < 4; ++e) s[v4 * 4 + e] += wv[e] * bf2f(av[e]);
      }
    }
  }
  const short* gp = hb + (size_t)n * 352 + 170 + c0;
  short* arow = act + ((size_t)b * 1024 + n) * 192 + c0;
#pragma unroll
  for (int v4 = 0; v4 < 3; ++v4) {
    short4v res;
#pragma unroll
    for (int e = 0; e < 4; ++e) {
      float sv = s[v4 * 4 + e];
      float ge = 0.5f * sv * (1.f + erff(sv * 0.70710678118654752f));
      res[e] = bfbits(ge * bf2f(gp[v4 * 4 + e]));
    }
    *reinterpret_cast<short4v*>(arow + v4 * 4) = res;
  }
}

// ---------------------------------------------------------------------------
extern "C" void kernel_launch(void* const* d_in, const int* in_sizes, int n_in,
                              void* d_out, int out_size, void* d_ws,
                              size_t ws_size, hipStream_t stream) {
  const float* x      = (const float*)d_in[0];
  const float* ln1_g  = (const float*)d_in[1];
  const float* ln1_b  = (const float*)d_in[2];
  const float* ln2_g  = (const float*)d_in[3];
  const float* ln2_b  = (const float*)d_in[4];
  const float* qkv_w  = (const float*)d_in[5];
  const float* qkv_bn = (const float*)d_in[6];
  const float* pe_w   = (const float*)d_in[7];
  const float* pe_bn  = (const float*)d_in[8];
  const float* proj_w = (const float*)d_in[9];
  const float* proj_bn= (const float*)d_in[10];
  const float* fc1_w  = (const float*)d_in[11];
  const float* fc1_b  = (const float*)d_in[12];
  const float* dw_w   = (const float*)d_in[13];
  const float* dw_b   = (const float*)d_in[14];
  const float* fc2_w  = (const float*)d_in[15];
  const float* fc2_b  = (const float*)d_in[16];

  char* base = (char*)d_ws;
  short* xn   = (short*)(base + 0);          // 4 MiB bf16 [b][n][256]
  short* qkv  = (short*)(base + 4194304);    // 8 MiB bf16 [b][n][512]
  short* obf  = (short*)(base + 12582912);   // 4 MiB bf16 [b][n][256]
  float* x1   = (float*)(base + 16777216);   // 8 MiB f32  [b][n][256]
  short* xn2  = (short*)(base + 25165824);   // 4 MiB bf16 [b][n][256]
  short* hbuf = (short*)(base + 29360128);   // 5.5 MiB bf16 [b][n][352]
  short* act  = (short*)(base + 35131392);   // 3 MiB bf16 [b][n][192]
  short* wq   = (short*)(base + 38277120);
  short* wpj  = (short*)(base + 38539264);
  short* wf1  = (short*)(base + 38670336);
  short* wf2  = (short*)(base + 38866944);
  float* pwT  = (float*)(base + 38965248);
  float* pbv  = (float*)(base + 38974464);
  float* wdT  = (float*)(base + 38975488);
  float* dbv  = (float*)(base + 38982400);
  float* bq   = (float*)(base + 38983168);
  float* bpj  = (float*)(base + 38985216);
  short* vT   = (short*)(base + 40894464);   // 4 MiB bf16 [b*8+h][32][1024]
  float* outp = (float*)d_out;

  hipLaunchKernelGGL(prep_kernel, dim3(1360), dim3(256), 0, stream, qkv_w,
                     qkv_bn, proj_w, proj_bn, fc1_w, fc2_w, pe_w, pe_bn, dw_w,
                     dw_b, wq, bq, wpj, bpj, wf1, wf2, pwT, pbv, wdT, dbv);
  hipLaunchKernelGGL(ln1_kernel, dim3(512), dim3(256), 0, stream, x, ln1_g,
                     ln1_b, xn);
  // qkv GEMM: OC=512, OT=4, dual-write V to vT
  hipLaunchKernelGGL((gemm6_kernel<3>), dim3(512), dim3(256), 0, stream, xn,
                     wq, bq, nullptr, nullptr, nullptr, qkv, vT, 512, 256, 4,
                     256, 512);
  // attention + PE fused
  hipLaunchKernelGGL(attn6_kernel, dim3(1024), dim3(256), 0, stream, qkv, vT,
                     pwT, pbv, obf);
  // proj GEMM: OC=256, OT=2, out x1 = proj + x
  hipLaunchKernelGGL((gemm6_kernel<1>), dim3(256), dim3(256), 0, stream, obf,
                     wpj, bpj, x, nullptr, nullptr, x1, nullptr, 256, 256, 2,
                     256, 256);
  hipLaunchKernelGGL(ln2_kernel, dim3(512), dim3(256), 0, stream, x1, ln2_g,
                     ln2_b, xn2);
  // fc1 GEMM: OC=340 (pad 384), OT=3, out hbuf stride 352
  hipLaunchKernelGGL((gemm6_kernel<0>), dim3(384), dim3(256), 0, stream, xn2,
                     wf1, fc1_b, nullptr, nullptr, nullptr, hbuf, nullptr, 340,
                     256, 3, 256, 352);
  hipLaunchKernelGGL(glu3_kernel, dim3(512), dim3(256), 0, stream, hbuf, wdT,
                     dbv, act);
  // fc2 GEMM: OC=256, K=192, OT=2, out = d_out + x1 + xn2
  hipLaunchKernelGGL((gemm6_kernel<2>), dim3(256), dim3(256), 0, stream, act,
                     wf2, fc2_b, nullptr, x1, xn2, outp, nullptr, 256, 192, 2,
                     192, 256);
}